// Round 1
// baseline (313.116 us; speedup 1.0000x reference)
//
#include <hip/hip_runtime.h>
#include <cstddef>
#include <cstdint>

// Problem dims
constexpr int Bv = 128;   // batch
constexpr int Sv = 256;   // src len
constexpr int Hv = 1024;  // hidden
constexpr int Ev = 512;   // embed
constexpr int Vv = 32000; // vocab

typedef __attribute__((ext_vector_type(4))) float f32x4;
typedef __attribute__((ext_vector_type(8))) short short8;
typedef __attribute__((ext_vector_type(4))) short short4v;

__device__ __forceinline__ unsigned short f2bf(float f) {
  unsigned u = __builtin_bit_cast(unsigned, f);
  u += 0x7fffu + ((u >> 16) & 1u);
  return (unsigned short)(u >> 16);
}

// ---------------------------------------------------------------------------
// Generic MFMA GEMM: C[m,n] = sum_k A1[m,k]*W1[n,k] (k<K1)
//                           + sum_k A2[m,k]*W2[n,k] (k<K2)  (+bias1[n]+bias2[n])
// M = 128 fixed. A row-major with lda; W row-major (N x K) with ldw.
// EPI: 0 = store, 1 = tanh then store.
// ---------------------------------------------------------------------------
template <int BN, int EPI>
__global__ __launch_bounds__(256, 2) void gemm_mfma(
    const float* __restrict__ A1, int lda1, int K1,
    const float* __restrict__ A2, int lda2, int K2,
    const float* __restrict__ W1, int ldw1,
    const float* __restrict__ W2, int ldw2,
    const float* __restrict__ bias1, const float* __restrict__ bias2,
    float* __restrict__ C, int ldc, int N) {
  constexpr int BM = 128, BK = 32, LP = 40;  // LP: LDS row pitch in bf16 (pad +8)
  constexpr int WAVES_N = (BN == 64) ? 2 : 1;
  constexpr int WM = (WAVES_N == 2) ? 64 : 32;
  constexpr int FM = WM / 16;
  constexpr int FN = 2;  // WN = 32 always
  constexpr int ACH = 4;               // A float4 chunks per thread
  constexpr int WCH = (BN * 8) / 256;  // W float4 chunks per thread

  __shared__ unsigned short Al[BM * LP];
  __shared__ unsigned short Wl[BN * LP];

  const int tid = threadIdx.x;
  const int wid = tid >> 6, lane = tid & 63;
  const int nBlock = blockIdx.x * BN;
  int wm, wn;
  if (WAVES_N == 2) { wm = (wid >> 1) * WM; wn = (wid & 1) * 32; }
  else              { wm = wid * WM;        wn = 0; }

  f32x4 acc[FM][FN] = {};

  const int KT = K1 + K2;
  for (int kg = 0; kg < KT; kg += BK) {
    const float* Aseg; int lda; const float* Wseg; int ldw; int kloc;
    if (kg < K1) { Aseg = A1; lda = lda1; Wseg = W1; ldw = ldw1; kloc = kg; }
    else         { Aseg = A2; lda = lda2; Wseg = W2; ldw = ldw2; kloc = kg - K1; }

    float4 av[ACH];
    float4 wv[WCH];
#pragma unroll
    for (int i = 0; i < ACH; i++) {
      int c = tid + i * 256;
      int m = c >> 3, kq = (c & 7) << 2;
      av[i] = *(const float4*)(Aseg + (size_t)m * lda + kloc + kq);
    }
#pragma unroll
    for (int i = 0; i < WCH; i++) {
      int c = tid + i * 256;
      int n = c >> 3, kq = (c & 7) << 2;
      wv[i] = *(const float4*)(Wseg + (size_t)(nBlock + n) * ldw + kloc + kq);
    }
    __syncthreads();  // previous iteration's fragment reads done
#pragma unroll
    for (int i = 0; i < ACH; i++) {
      int c = tid + i * 256;
      int m = c >> 3, kq = (c & 7) << 2;
      short4v s = {(short)f2bf(av[i].x), (short)f2bf(av[i].y),
                   (short)f2bf(av[i].z), (short)f2bf(av[i].w)};
      *(short4v*)&Al[m * LP + kq] = s;
    }
#pragma unroll
    for (int i = 0; i < WCH; i++) {
      int c = tid + i * 256;
      int n = c >> 3, kq = (c & 7) << 2;
      short4v s = {(short)f2bf(wv[i].x), (short)f2bf(wv[i].y),
                   (short)f2bf(wv[i].z), (short)f2bf(wv[i].w)};
      *(short4v*)&Wl[n * LP + kq] = s;
    }
    __syncthreads();

    const int klane = (lane >> 4) << 3;
    const int r = lane & 15;
    short8 af[FM], wf[FN];
#pragma unroll
    for (int f = 0; f < FM; f++)
      af[f] = *(const short8*)&Al[(wm + f * 16 + r) * LP + klane];
#pragma unroll
    for (int f = 0; f < FN; f++)
      wf[f] = *(const short8*)&Wl[(wn + f * 16 + r) * LP + klane];
#pragma unroll
    for (int fm = 0; fm < FM; fm++)
#pragma unroll
      for (int fn = 0; fn < FN; fn++)
        acc[fm][fn] = __builtin_amdgcn_mfma_f32_16x16x32_bf16(
            af[fm], wf[fn], acc[fm][fn], 0, 0, 0);
  }

  // Epilogue. D layout: col = lane&15, row = (lane>>4)*4 + j
  const int col = lane & 15, rb = (lane >> 4) << 2;
#pragma unroll
  for (int fn = 0; fn < FN; fn++) {
    int n = nBlock + wn + fn * 16 + col;
    float bsum = 0.f;
    if (bias1) bsum += bias1[n];
    if (bias2) bsum += bias2[n];
#pragma unroll
    for (int fm = 0; fm < FM; fm++) {
#pragma unroll
      for (int j = 0; j < 4; j++) {
        int m = wm + fm * 16 + rb + j;
        float v = acc[fm][fn][j] + bsum;
        if (EPI == 1) v = tanhf(v);
        C[(size_t)m * ldc + n] = v;
      }
    }
  }
}

// ---------------------------------------------------------------------------
__global__ void gather_emb(const int* __restrict__ ids,
                           const float* __restrict__ emb,
                           float* __restrict__ x) {
  int idx = blockIdx.x * 256 + threadIdx.x;  // B*E = 65536
  int b = idx >> 9, e = idx & 511;
  x[idx] = emb[(size_t)ids[b] * Ev + e];
}

__global__ void lstm_pw(const float* __restrict__ G,
                        const float* __restrict__ c_prev,
                        float* __restrict__ h_ws,
                        float* __restrict__ h_out,
                        float* __restrict__ c_out) {
  int idx = blockIdx.x * 256 + threadIdx.x;  // B*H = 131072
  int b = idx >> 10, j = idx & 1023;
  const float* g = G + (size_t)b * 4096;
  float gi = g[j], gf = g[1024 + j], gg = g[2048 + j], go = g[3072 + j];
  float c = c_prev[idx];
  float si = 1.f / (1.f + expf(-gi));
  float sf = 1.f / (1.f + expf(-gf));
  float so = 1.f / (1.f + expf(-go));
  float cn = sf * c + si * tanhf(gg);
  float hn = so * tanhf(cn);
  h_ws[idx] = hn;
  h_out[idx] = hn;
  c_out[idx] = cn;
}

__global__ void transpose1024(const float* __restrict__ W,
                              float* __restrict__ WT) {
  __shared__ float t[32][33];
  int bx = blockIdx.x * 32, by = blockIdx.y * 32;
  int tx = threadIdx.x, ty = threadIdx.y;  // (32, 8)
#pragma unroll
  for (int i = 0; i < 32; i += 8)
    t[ty + i][tx] = W[(size_t)(by + ty + i) * Hv + bx + tx];
  __syncthreads();
#pragma unroll
  for (int i = 0; i < 32; i += 8)
    WT[(size_t)(bx + ty + i) * Hv + by + tx] = t[tx][ty + i];
}

__global__ void dot_b(const float* __restrict__ attn_b,
                      const float* __restrict__ rnn,
                      float* __restrict__ cb) {
  int b = blockIdx.x, lane = threadIdx.x;  // 64 threads
  const float4* r4 = (const float4*)(rnn + (size_t)b * Hv);
  const float4* a4 = (const float4*)attn_b;
  float s = 0.f;
#pragma unroll
  for (int i = lane; i < 256; i += 64) {
    float4 r = r4[i], a = a4[i];
    s += r.x * a.x + r.y * a.y + r.z * a.z + r.w * a.w;
  }
#pragma unroll
  for (int o = 32; o; o >>= 1) s += __shfl_xor(s, o);
  if (lane == 0) cb[b] = s;
}

__global__ void scores_k(const float* __restrict__ enc,
                         const float* __restrict__ q,
                         const float* __restrict__ cb,
                         float* __restrict__ sc) {
  int blk = blockIdx.x;           // B * S/4 = 8192
  int b = blk >> 6, s4 = blk & 63;
  int wid = threadIdx.x >> 6, lane = threadIdx.x & 63;
  int s = s4 * 4 + wid;
  const float4* e4 = (const float4*)(enc + ((size_t)s * Bv + b) * Hv);
  const float4* q4 = (const float4*)(q + (size_t)b * Hv);
  float sum = 0.f;
#pragma unroll
  for (int i = 0; i < 4; i++) {
    int idx = lane + i * 64;
    float4 e = e4[idx], qq = q4[idx];
    sum += e.x * qq.x + e.y * qq.y + e.z * qq.z + e.w * qq.w;
  }
#pragma unroll
  for (int o = 32; o; o >>= 1) sum += __shfl_xor(sum, o);
  if (lane == 0) sc[(size_t)b * Sv + s] = sum + cb[b];
}

__global__ void softmax_k(const float* __restrict__ sc,
                          float* __restrict__ attn) {
  int b = blockIdx.x, t = threadIdx.x;  // 256 threads = S
  __shared__ float r1[4], r2[4];
  float v = sc[(size_t)b * Sv + t];
  float m = v;
#pragma unroll
  for (int o = 32; o; o >>= 1) m = fmaxf(m, __shfl_xor(m, o));
  if ((t & 63) == 0) r1[t >> 6] = m;
  __syncthreads();
  m = fmaxf(fmaxf(r1[0], r1[1]), fmaxf(r1[2], r1[3]));
  float e = expf(v - m);
  float ssum = e;
#pragma unroll
  for (int o = 32; o; o >>= 1) ssum += __shfl_xor(ssum, o);
  if ((t & 63) == 0) r2[t >> 6] = ssum;
  __syncthreads();
  ssum = (r2[0] + r2[1]) + (r2[2] + r2[3]);
  attn[(size_t)b * Sv + t] = e / ssum;
}

__global__ void context_k(const float* __restrict__ attn,
                          const float* __restrict__ enc,
                          float* __restrict__ ctx) {
  int blk = blockIdx.x;                 // B * 4 = 512
  int b = blk >> 2, hc = (blk & 3) * 256;
  int t = threadIdx.x;
  int h = hc + t;
  __shared__ float a[256];
  a[t] = attn[(size_t)b * Sv + t];
  __syncthreads();
  float s = 0.f;
#pragma unroll 8
  for (int si = 0; si < 256; si++)
    s += a[si] * enc[((size_t)si * Bv + b) * Hv + h];
  ctx[(size_t)b * Hv + h] = s;
}

// ---------------------------------------------------------------------------
extern "C" void kernel_launch(void* const* d_in, const int* in_sizes, int n_in,
                              void* d_out, int out_size, void* d_ws,
                              size_t ws_size, hipStream_t stream) {
  const int*   ids      = (const int*)d_in[0];
  const float* h0       = (const float*)d_in[1];
  const float* c0       = (const float*)d_in[2];
  const float* enc      = (const float*)d_in[3];
  const float* emb      = (const float*)d_in[4];
  const float* w_ih0    = (const float*)d_in[5];
  const float* w_hh0    = (const float*)d_in[6];
  const float* b_ih0    = (const float*)d_in[7];
  const float* b_hh0    = (const float*)d_in[8];
  const float* w_ih1    = (const float*)d_in[9];
  const float* w_hh1    = (const float*)d_in[10];
  const float* b_ih1    = (const float*)d_in[11];
  const float* b_hh1    = (const float*)d_in[12];
  const float* attn_w   = (const float*)d_in[13];
  const float* attn_b   = (const float*)d_in[14];
  const float* concat_w = (const float*)d_in[15];
  const float* concat_b = (const float*)d_in[16];
  const float* out_w    = (const float*)d_in[17];
  const float* out_b    = (const float*)d_in[18];

  float* logits = (float*)d_out;                  // [128, 32000]
  float* hout   = logits + (size_t)Bv * Vv;       // [2, 128, 1024]
  float* cout   = hout + 2 * Bv * Hv;             // [2, 128, 1024]

  float* ws = (float*)d_ws;
  float* x      = ws;                 // 65536
  float* G      = x + 65536;          // 524288
  float* h_a    = G + 524288;         // 131072
  float* h_b    = h_a + 131072;       // 131072
  float* ctx    = h_b + 131072;       // 131072
  float* q      = ctx + 131072;       // 131072
  float* cb     = q + 131072;         // 128
  float* scores = cb + 128;           // 32768
  float* attn   = scores + 32768;     // 32768
  float* awT    = attn + 32768;       // 1048576
  float* cat    = awT + 1048576;      // 131072

  // 1. embedding gather
  gather_emb<<<256, 256, 0, stream>>>(ids, emb, x);
  // 2. LSTM layer 0 gates
  gemm_mfma<32, 0><<<128, 256, 0, stream>>>(
      x, Ev, Ev, h0, Hv, Hv, w_ih0, Ev, w_hh0, Hv, b_ih0, b_hh0, G, 4 * Hv, 4 * Hv);
  // 3. LSTM layer 0 pointwise
  lstm_pw<<<512, 256, 0, stream>>>(G, c0, h_a, hout, cout);
  // 4. LSTM layer 1 gates
  gemm_mfma<32, 0><<<128, 256, 0, stream>>>(
      h_a, Hv, Hv, h0 + Bv * Hv, Hv, Hv, w_ih1, Hv, w_hh1, Hv, b_ih1, b_hh1,
      G, 4 * Hv, 4 * Hv);
  // 5. LSTM layer 1 pointwise
  lstm_pw<<<512, 256, 0, stream>>>(G, c0 + Bv * Hv, h_b, hout + Bv * Hv,
                                   cout + Bv * Hv);
  // 6. transpose attn_w for q GEMM
  transpose1024<<<dim3(32, 32), dim3(32, 8), 0, stream>>>(attn_w, awT);
  // 7. q = rnn @ attn_w
  gemm_mfma<32, 0><<<32, 256, 0, stream>>>(
      h_b, Hv, Hv, nullptr, 0, 0, awT, Hv, nullptr, 0, nullptr, nullptr,
      q, Hv, Hv);
  // 8. cb[b] = <attn_b, rnn[b]>
  dot_b<<<128, 64, 0, stream>>>(attn_b, h_b, cb);
  // 9. scores
  scores_k<<<8192, 256, 0, stream>>>(enc, q, cb, scores);
  // 10. softmax
  softmax_k<<<128, 256, 0, stream>>>(scores, attn);
  // 11. context
  context_k<<<512, 256, 0, stream>>>(attn, enc, ctx);
  // 12. concat + tanh
  gemm_mfma<32, 1><<<32, 256, 0, stream>>>(
      h_b, Hv, Hv, ctx, Hv, Hv, concat_w, 2 * Hv, concat_w + Hv, 2 * Hv,
      concat_b, nullptr, cat, Hv, Hv);
  // 13. logits
  gemm_mfma<64, 0><<<500, 256, 0, stream>>>(
      cat, Hv, Hv, nullptr, 0, 0, out_w, Hv, nullptr, 0, out_b, nullptr,
      logits, Vv, Vv);
}

// Round 2
// 302.490 us; speedup vs baseline: 1.0351x; 1.0351x over previous
//
#include <hip/hip_runtime.h>
#include <cstddef>
#include <cstdint>

// Problem dims
constexpr int Bv = 128;   // batch
constexpr int Sv = 256;   // src len
constexpr int Hv = 1024;  // hidden
constexpr int Ev = 512;   // embed
constexpr int Vv = 32000; // vocab

typedef __attribute__((ext_vector_type(4))) float f32x4;
typedef __attribute__((ext_vector_type(8))) short short8;
typedef __attribute__((ext_vector_type(4))) short short4v;

__device__ __forceinline__ unsigned short f2bf(float f) {
  unsigned u = __builtin_bit_cast(unsigned, f);
  u += 0x7fffu + ((u >> 16) & 1u);
  return (unsigned short)(u >> 16);
}

// ---------------------------------------------------------------------------
// MFMA GEMM: C[m,n] = sum_k A1[m,k]*W1[n,k] (k<K1) + sum_k A2[m,k]*W2[n,k]
//            (+bias1[n]+bias2[n]); EPI==1 applies tanh.
// M covered by gridDim.y blocks of BM. W row-major [N,K] unless WTR (then
// W1 is [K,N], transposed during LDS staging; requires K2==0, BN==32).
// GATHER: A1 row m is emb[ids[m]].
// Register-prefetch: tile k+1 is loaded into regs while tile k's fragments
// are read from LDS and fed to MFMA.
// ---------------------------------------------------------------------------
template <int BM, int BN, int EPI, int WTR, int GATHER>
__global__ __launch_bounds__(256, 2) void gemm_mfma(
    const int* __restrict__ ids,
    const float* __restrict__ A1, int lda1, int K1,
    const float* __restrict__ A2, int lda2, int K2,
    const float* __restrict__ W1, int ldw1,
    const float* __restrict__ W2, int ldw2,
    const float* __restrict__ bias1, const float* __restrict__ bias2,
    float* __restrict__ C, int ldc, int N) {
  constexpr int BK = 32, LP = 40;  // LDS row pitch (bf16), +8 pad
  constexpr int WAVES_N = (BN >= 64) ? 2 : 1;
  constexpr int WAVES_M = 4 / WAVES_N;
  constexpr int WM = BM / WAVES_M;
  constexpr int FM = WM / 16;
  constexpr int FN = 2;  // WN = 32
  constexpr int ACH = (BM * BK) / (4 * 256);
  constexpr int WCH = (BN * BK) / (4 * 256);

  __shared__ unsigned short Al[BM * LP];
  __shared__ unsigned short Wl[BN * LP];

  const int tid = threadIdx.x;
  const int wid = tid >> 6, lane = tid & 63;
  const int nBlock = blockIdx.x * BN;
  const int mBlock = blockIdx.y * BM;
  int wm, wn;
  if (WAVES_N == 2) { wm = (wid >> 1) * WM; wn = (wid & 1) * 32; }
  else              { wm = wid * WM;        wn = 0; }

  float4 av[ACH], wv[WCH];

  auto load_tile = [&](int kg) {
    const bool seg1 = kg < K1;
    const float* Wseg = seg1 ? W1 : W2;
    const int ldw = seg1 ? ldw1 : ldw2;
    const int kloc = seg1 ? kg : kg - K1;
#pragma unroll
    for (int i = 0; i < ACH; i++) {
      int c = tid + i * 256;
      int m = c >> 3, kq = (c & 7) << 2;
      const float* arow;
      if (seg1) {
        if (GATHER) arow = A1 + (size_t)ids[mBlock + m] * lda1;
        else        arow = A1 + (size_t)(mBlock + m) * lda1;
      } else {
        arow = A2 + (size_t)(mBlock + m) * lda2;
      }
      av[i] = *(const float4*)(arow + kloc + kq);
    }
    if (WTR) {
      int row = tid >> 3, colq = tid & 7;  // 32 k-rows x 8 n-quads
      wv[0] = *(const float4*)(Wseg + (size_t)(kloc + row) * ldw + nBlock + colq * 4);
    } else {
#pragma unroll
      for (int i = 0; i < WCH; i++) {
        int c = tid + i * 256;
        int n = c >> 3, kq = (c & 7) << 2;
        wv[i] = *(const float4*)(Wseg + (size_t)(nBlock + n) * ldw + kloc + kq);
      }
    }
  };

  const int KT = K1 + K2;
  const int NS = KT / BK;
  load_tile(0);
  f32x4 acc[FM][FN] = {};

  for (int step = 0; step < NS; ++step) {
    __syncthreads();  // previous iteration's fragment reads done
    // commit regs -> LDS (f32 -> bf16)
#pragma unroll
    for (int i = 0; i < ACH; i++) {
      int c = tid + i * 256;
      int m = c >> 3, kq = (c & 7) << 2;
      short4v s = {(short)f2bf(av[i].x), (short)f2bf(av[i].y),
                   (short)f2bf(av[i].z), (short)f2bf(av[i].w)};
      *(short4v*)&Al[m * LP + kq] = s;
    }
    if (WTR) {
      int row = tid >> 3, colq = tid & 7;
      Wl[(colq * 4 + 0) * LP + row] = f2bf(wv[0].x);
      Wl[(colq * 4 + 1) * LP + row] = f2bf(wv[0].y);
      Wl[(colq * 4 + 2) * LP + row] = f2bf(wv[0].z);
      Wl[(colq * 4 + 3) * LP + row] = f2bf(wv[0].w);
    } else {
#pragma unroll
      for (int i = 0; i < WCH; i++) {
        int c = tid + i * 256;
        int n = c >> 3, kq = (c & 7) << 2;
        short4v s = {(short)f2bf(wv[i].x), (short)f2bf(wv[i].y),
                     (short)f2bf(wv[i].z), (short)f2bf(wv[i].w)};
        *(short4v*)&Wl[n * LP + kq] = s;
      }
    }
    __syncthreads();

    if (step + 1 < NS) load_tile((step + 1) * BK);  // prefetch overlaps MFMA

    const int klane = (lane >> 4) << 3;
    const int r = lane & 15;
    short8 af[FM], wf[FN];
#pragma unroll
    for (int f = 0; f < FM; f++)
      af[f] = *(const short8*)&Al[(wm + f * 16 + r) * LP + klane];
#pragma unroll
    for (int f = 0; f < FN; f++)
      wf[f] = *(const short8*)&Wl[(wn + f * 16 + r) * LP + klane];
#pragma unroll
    for (int fm = 0; fm < FM; fm++)
#pragma unroll
      for (int fn = 0; fn < FN; fn++)
        acc[fm][fn] = __builtin_amdgcn_mfma_f32_16x16x32_bf16(
            af[fm], wf[fn], acc[fm][fn], 0, 0, 0);
  }

  // Epilogue. D layout: col = lane&15, row = (lane>>4)*4 + j
  const int col = lane & 15, rb = (lane >> 4) << 2;
#pragma unroll
  for (int fn = 0; fn < FN; fn++) {
    int n = nBlock + wn + fn * 16 + col;
    float bsum = 0.f;
    if (bias1) bsum += bias1[n];
    if (bias2) bsum += bias2[n];
#pragma unroll
    for (int fm = 0; fm < FM; fm++) {
#pragma unroll
      for (int j = 0; j < 4; j++) {
        int m = mBlock + wm + fm * 16 + rb + j;
        float v = acc[fm][fn][j] + bsum;
        if (EPI == 1) v = tanhf(v);
        C[(size_t)m * ldc + n] = v;
      }
    }
  }
}

// ---------------------------------------------------------------------------
__global__ void lstm_pw(const float* __restrict__ G,
                        const float* __restrict__ c_prev,
                        float* __restrict__ h_out,
                        float* __restrict__ c_out) {
  int idx = blockIdx.x * 256 + threadIdx.x;  // B*H = 131072
  int b = idx >> 10, j = idx & 1023;
  const float* g = G + (size_t)b * 4096;
  float gi = g[j], gf = g[1024 + j], gg = g[2048 + j], go = g[3072 + j];
  float c = c_prev[idx];
  float si = 1.f / (1.f + expf(-gi));
  float sf = 1.f / (1.f + expf(-gf));
  float so = 1.f / (1.f + expf(-go));
  float cn = sf * c + si * tanhf(gg);
  float hn = so * tanhf(cn);
  h_out[idx] = hn;
  c_out[idx] = cn;
}

// ---------------------------------------------------------------------------
// Fused attention: per b, scores = <enc[s,b,:], q[b]> + <attn_b, rnn[b]>,
// softmax over s, then ctx[b,:] = sum_s attn[s] * enc[s,b,:].
// Block streams enc[:,b,:] (1 MB) once for scores; context re-read hits L2.
// ---------------------------------------------------------------------------
__global__ __launch_bounds__(1024, 2) void attn_fused(
    const float* __restrict__ enc, const float* __restrict__ q,
    const float* __restrict__ rnn, const float* __restrict__ attn_b,
    float* __restrict__ ctx) {
  const int b = blockIdx.x;
  const int t = threadIdx.x;
  const int wid = t >> 6, lane = t & 63;
  __shared__ float qs[1024];
  __shared__ float sc[256];
  __shared__ float red[16];
  __shared__ float redm[4], reds[4];

  qs[t] = q[(size_t)b * Hv + t];
  float cbp = attn_b[t] * rnn[(size_t)b * Hv + t];
#pragma unroll
  for (int o = 32; o; o >>= 1) cbp += __shfl_xor(cbp, o);
  if (lane == 0) red[wid] = cbp;
  __syncthreads();
  float cb = 0.f;
#pragma unroll
  for (int i = 0; i < 16; i++) cb += red[i];

  // scores: 16 waves x 16 s each, wave-dot over H
  for (int si = wid; si < Sv; si += 16) {
    const float4* e4 = (const float4*)(enc + ((size_t)si * Bv + b) * Hv);
    const float4* q4 = (const float4*)qs;
    float s = 0.f;
#pragma unroll
    for (int i = 0; i < 4; i++) {
      float4 e = e4[lane + i * 64], qq = q4[lane + i * 64];
      s += e.x * qq.x + e.y * qq.y + e.z * qq.z + e.w * qq.w;
    }
#pragma unroll
    for (int o = 32; o; o >>= 1) s += __shfl_xor(s, o);
    if (lane == 0) sc[si] = s + cb;
  }
  __syncthreads();

  // softmax over sc[256] (threads 0..255)
  if (t < 256) {
    float v = sc[t];
    float m = v;
#pragma unroll
    for (int o = 32; o; o >>= 1) m = fmaxf(m, __shfl_xor(m, o));
    if (lane == 0) redm[t >> 6] = m;
  }
  __syncthreads();
  if (t < 256) {
    float m = fmaxf(fmaxf(redm[0], redm[1]), fmaxf(redm[2], redm[3]));
    float e = expf(sc[t] - m);
    float s = e;
#pragma unroll
    for (int o = 32; o; o >>= 1) s += __shfl_xor(s, o);
    if (lane == 0) reds[t >> 6] = s;
    qs[t] = e;  // stash numerator (qs no longer needed)
  }
  __syncthreads();
  if (t < 256) {
    float denom = (reds[0] + reds[1]) + (reds[2] + reds[3]);
    sc[t] = qs[t] / denom;
  }
  __syncthreads();

  // context: thread t owns h=t
  float acc = 0.f;
  const float* ebase = enc + (size_t)b * Hv + t;
#pragma unroll 4
  for (int s = 0; s < Sv; s++)
    acc += sc[s] * ebase[(size_t)s * Bv * Hv];
  ctx[(size_t)b * Hv + t] = acc;
}

// ---------------------------------------------------------------------------
extern "C" void kernel_launch(void* const* d_in, const int* in_sizes, int n_in,
                              void* d_out, int out_size, void* d_ws,
                              size_t ws_size, hipStream_t stream) {
  const int*   ids      = (const int*)d_in[0];
  const float* h0       = (const float*)d_in[1];
  const float* c0       = (const float*)d_in[2];
  const float* enc      = (const float*)d_in[3];
  const float* emb      = (const float*)d_in[4];
  const float* w_ih0    = (const float*)d_in[5];
  const float* w_hh0    = (const float*)d_in[6];
  const float* b_ih0    = (const float*)d_in[7];
  const float* b_hh0    = (const float*)d_in[8];
  const float* w_ih1    = (const float*)d_in[9];
  const float* w_hh1    = (const float*)d_in[10];
  const float* b_ih1    = (const float*)d_in[11];
  const float* b_hh1    = (const float*)d_in[12];
  const float* attn_w   = (const float*)d_in[13];
  const float* attn_b   = (const float*)d_in[14];
  const float* concat_w = (const float*)d_in[15];
  const float* concat_b = (const float*)d_in[16];
  const float* out_w    = (const float*)d_in[17];
  const float* out_b    = (const float*)d_in[18];

  float* logits = (float*)d_out;                  // [128, 32000]
  float* hout   = logits + (size_t)Bv * Vv;       // [2, 128, 1024]
  float* cout   = hout + 2 * Bv * Hv;             // [2, 128, 1024]

  float* ws  = (float*)d_ws;
  float* G   = ws;            // 524288
  float* ctx = G + 524288;    // 131072
  float* q   = ctx + 131072;  // 131072
  float* cat = q + 131072;    // 131072

  // 1. LSTM layer 0 gates (embedding gather fused into A-load)
  gemm_mfma<64, 32, 0, 0, 1><<<dim3(128, 2), 256, 0, stream>>>(
      ids, emb, Ev, Ev, h0, Hv, Hv, w_ih0, Ev, w_hh0, Hv, b_ih0, b_hh0,
      G, 4 * Hv, 4 * Hv);
  // 2. LSTM layer 0 pointwise -> writes h directly into d_out
  lstm_pw<<<512, 256, 0, stream>>>(G, c0, hout, cout);
  // 3. LSTM layer 1 gates
  gemm_mfma<64, 32, 0, 0, 0><<<dim3(128, 2), 256, 0, stream>>>(
      nullptr, hout, Hv, Hv, h0 + Bv * Hv, Hv, Hv, w_ih1, Hv, w_hh1, Hv,
      b_ih1, b_hh1, G, 4 * Hv, 4 * Hv);
  // 4. LSTM layer 1 pointwise
  lstm_pw<<<512, 256, 0, stream>>>(G, c0 + Bv * Hv, hout + Bv * Hv,
                                   cout + Bv * Hv);
  // 5. q = rnn @ attn_w  (attn_w transposed during LDS staging)
  gemm_mfma<64, 32, 0, 1, 0><<<dim3(32, 2), 256, 0, stream>>>(
      nullptr, hout + Bv * Hv, Hv, Hv, nullptr, 0, 0, attn_w, Hv,
      nullptr, 0, nullptr, nullptr, q, Hv, Hv);
  // 6. fused attention (scores + bias-dot + softmax + context)
  attn_fused<<<128, 1024, 0, stream>>>(enc, q, hout + Bv * Hv, attn_b, ctx);
  // 7. concat + tanh
  gemm_mfma<64, 32, 1, 0, 0><<<dim3(32, 2), 256, 0, stream>>>(
      nullptr, hout + Bv * Hv, Hv, Hv, ctx, Hv, Hv, concat_w, 2 * Hv,
      concat_w + Hv, 2 * Hv, concat_b, nullptr, cat, Hv, Hv);
  // 8. logits
  gemm_mfma<128, 64, 0, 0, 0><<<dim3(500, 1), 256, 0, stream>>>(
      nullptr, cat, Hv, Hv, nullptr, 0, 0, out_w, Hv, nullptr, 0,
      out_b, nullptr, logits, Vv, Vv);
}

// Round 3
// 184.013 us; speedup vs baseline: 1.7016x; 1.6439x over previous
//
#include <hip/hip_runtime.h>
#include <cstddef>
#include <cstdint>

// Problem dims
constexpr int Bv = 128;   // batch
constexpr int Sv = 256;   // src len
constexpr int Hv = 1024;  // hidden
constexpr int Ev = 512;   // embed
constexpr int Vv = 32000; // vocab

typedef __attribute__((ext_vector_type(4))) float f32x4;
typedef __attribute__((ext_vector_type(8))) short short8;
typedef __attribute__((ext_vector_type(4))) short short4v;

__device__ __forceinline__ unsigned short f2bf(float f) {
  unsigned u = __builtin_bit_cast(unsigned, f);
  u += 0x7fffu + ((u >> 16) & 1u);
  return (unsigned short)(u >> 16);
}

// ---------------------------------------------------------------------------
// MFMA GEMM with split-K partials:
//   Cp[z][m,n] = sum_{k in split z} A[m,k]*W[n,k]  (+bias on z==0)
// A = A1 (k<K1, optionally gathered emb rows) then A2. W row-major [N,K]
// unless WTR (W1 is [K,N], transposed during LDS staging).
// Partial z written at C + z*gridDim.y*BM*ldc. Consumers sum partials.
// ---------------------------------------------------------------------------
template <int BM, int BN, int SPLIT, int WTR, int GATHER, int MINW>
__global__ __launch_bounds__(256, MINW) void gemm_mfma(
    const int* __restrict__ ids,
    const float* __restrict__ A1, int lda1, int K1,
    const float* __restrict__ A2, int lda2, int K2,
    const float* __restrict__ W1, int ldw1,
    const float* __restrict__ W2, int ldw2,
    const float* __restrict__ bias1, const float* __restrict__ bias2,
    float* __restrict__ C, int ldc, int N) {
  constexpr int BK = 32, LP = 40;  // LDS row pitch (bf16), +8 pad
  constexpr int WAVES_N = (BN >= 64) ? 2 : 1;
  constexpr int WAVES_M = 4 / WAVES_N;
  constexpr int WM = BM / WAVES_M;
  constexpr int FM = WM / 16;
  constexpr int FN = 2;  // WN = 32
  constexpr int ACH = (BM * BK) / (4 * 256);
  constexpr int WCH = (BN * BK) / (4 * 256);

  __shared__ unsigned short Al[BM * LP];
  __shared__ unsigned short Wl[BN * LP];

  const int tid = threadIdx.x;
  const int wid = tid >> 6, lane = tid & 63;
  const int nBlock = blockIdx.x * BN;
  const int mBlock = blockIdx.y * BM;
  const int z = blockIdx.z;
  int wm, wn;
  if (WAVES_N == 2) { wm = (wid >> 1) * WM; wn = (wid & 1) * 32; }
  else              { wm = wid * WM;        wn = 0; }

  float4 av[ACH], wv[WCH];

  auto load_tile = [&](int kg) {
    const bool seg1 = kg < K1;
    const float* Wseg = seg1 ? W1 : W2;
    const int ldw = seg1 ? ldw1 : ldw2;
    const int kloc = seg1 ? kg : kg - K1;
#pragma unroll
    for (int i = 0; i < ACH; i++) {
      int c = tid + i * 256;
      int m = c >> 3, kq = (c & 7) << 2;
      const float* arow;
      if (seg1) {
        if (GATHER) arow = A1 + (size_t)ids[mBlock + m] * lda1;
        else        arow = A1 + (size_t)(mBlock + m) * lda1;
      } else {
        arow = A2 + (size_t)(mBlock + m) * lda2;
      }
      av[i] = *(const float4*)(arow + kloc + kq);
    }
    if (WTR) {
      int row = tid >> 3, colq = tid & 7;  // 32 k-rows x 8 n-quads
      wv[0] = *(const float4*)(Wseg + (size_t)(kloc + row) * ldw + nBlock + colq * 4);
    } else {
#pragma unroll
      for (int i = 0; i < WCH; i++) {
        int c = tid + i * 256;
        int n = c >> 3, kq = (c & 7) << 2;
        wv[i] = *(const float4*)(Wseg + (size_t)(nBlock + n) * ldw + kloc + kq);
      }
    }
  };

  const int KT = K1 + K2;
  const int KS = KT / SPLIT;          // per-split K (multiple of BK; segment-aligned)
  const int kbeg = z * KS;
  const int NS = KS / BK;
  load_tile(kbeg);
  f32x4 acc[FM][FN] = {};

  for (int step = 0; step < NS; ++step) {
    __syncthreads();  // previous iteration's fragment reads done
    // commit regs -> LDS (f32 -> bf16)
#pragma unroll
    for (int i = 0; i < ACH; i++) {
      int c = tid + i * 256;
      int m = c >> 3, kq = (c & 7) << 2;
      short4v s = {(short)f2bf(av[i].x), (short)f2bf(av[i].y),
                   (short)f2bf(av[i].z), (short)f2bf(av[i].w)};
      *(short4v*)&Al[m * LP + kq] = s;
    }
    if (WTR) {
      int row = tid >> 3, colq = tid & 7;
      Wl[(colq * 4 + 0) * LP + row] = f2bf(wv[0].x);
      Wl[(colq * 4 + 1) * LP + row] = f2bf(wv[0].y);
      Wl[(colq * 4 + 2) * LP + row] = f2bf(wv[0].z);
      Wl[(colq * 4 + 3) * LP + row] = f2bf(wv[0].w);
    } else {
#pragma unroll
      for (int i = 0; i < WCH; i++) {
        int c = tid + i * 256;
        int n = c >> 3, kq = (c & 7) << 2;
        short4v s = {(short)f2bf(wv[i].x), (short)f2bf(wv[i].y),
                     (short)f2bf(wv[i].z), (short)f2bf(wv[i].w)};
        *(short4v*)&Wl[n * LP + kq] = s;
      }
    }
    __syncthreads();

    if (step + 1 < NS) load_tile(kbeg + (step + 1) * BK);  // prefetch

    const int klane = (lane >> 4) << 3;
    const int r = lane & 15;
    short8 af[FM], wf[FN];
#pragma unroll
    for (int f = 0; f < FM; f++)
      af[f] = *(const short8*)&Al[(wm + f * 16 + r) * LP + klane];
#pragma unroll
    for (int f = 0; f < FN; f++)
      wf[f] = *(const short8*)&Wl[(wn + f * 16 + r) * LP + klane];
#pragma unroll
    for (int fm = 0; fm < FM; fm++)
#pragma unroll
      for (int fn = 0; fn < FN; fn++)
        acc[fm][fn] = __builtin_amdgcn_mfma_f32_16x16x32_bf16(
            af[fm], wf[fn], acc[fm][fn], 0, 0, 0);
  }

  // Epilogue. D layout: col = lane&15, row = (lane>>4)*4 + j
  float* Cp = C + (size_t)z * gridDim.y * BM * ldc;
  const int col = lane & 15, rb = (lane >> 4) << 2;
#pragma unroll
  for (int fn = 0; fn < FN; fn++) {
    int n = nBlock + wn + fn * 16 + col;
    float bsum = 0.f;
    if (z == 0) {
      if (bias1) bsum += bias1[n];
      if (bias2) bsum += bias2[n];
    }
#pragma unroll
    for (int fm = 0; fm < FM; fm++) {
#pragma unroll
      for (int j = 0; j < 4; j++) {
        int m = mBlock + wm + fm * 16 + rb + j;
        Cp[(size_t)m * ldc + n] = acc[fm][fn][j] + bsum;
      }
    }
  }
}

// ---------------------------------------------------------------------------
template <int P>
__global__ void lstm_pw(const float* __restrict__ Gp,
                        const float* __restrict__ c_prev,
                        float* __restrict__ h_out,
                        float* __restrict__ c_out) {
  int idx = blockIdx.x * 256 + threadIdx.x;  // B*H = 131072
  int b = idx >> 10, j = idx & 1023;
  float gi = 0.f, gf = 0.f, gg = 0.f, go = 0.f;
#pragma unroll
  for (int p = 0; p < P; p++) {
    const float* g = Gp + (size_t)p * Bv * 4 * Hv + (size_t)b * 4096;
    gi += g[j]; gf += g[1024 + j]; gg += g[2048 + j]; go += g[3072 + j];
  }
  float c = c_prev[idx];
  float si = 1.f / (1.f + expf(-gi));
  float sf = 1.f / (1.f + expf(-gf));
  float so = 1.f / (1.f + expf(-go));
  float cn = sf * c + si * tanhf(gg);
  float hn = so * tanhf(cn);
  h_out[idx] = hn;
  c_out[idx] = cn;
}

// ---------------------------------------------------------------------------
// scores[b,s] = <enc[s,b,:], q[b,:]>  where q = sum of 4 split-K partials.
// (The <attn_b, rnn[b]> term is constant over s -> cancels in softmax.)
__global__ void scores_k(const float* __restrict__ enc,
                         const float* __restrict__ qp,
                         float* __restrict__ sc) {
  int blk = blockIdx.x;           // B * S/4 = 8192
  int b = blk >> 6, s4 = blk & 63;
  int wid = threadIdx.x >> 6, lane = threadIdx.x & 63;
  int s = s4 * 4 + wid;
  const float4* e4 = (const float4*)(enc + ((size_t)s * Bv + b) * Hv);
  const float4* q0 = (const float4*)(qp + (size_t)b * Hv);
  const float4* q1 = (const float4*)(qp + 1 * Bv * Hv + (size_t)b * Hv);
  const float4* q2 = (const float4*)(qp + 2 * Bv * Hv + (size_t)b * Hv);
  const float4* q3 = (const float4*)(qp + 3 * Bv * Hv + (size_t)b * Hv);
  float sum = 0.f;
#pragma unroll
  for (int i = 0; i < 4; i++) {
    int idx = lane + i * 64;
    float4 e = e4[idx];
    float4 a = q0[idx], bq = q1[idx], c = q2[idx], d = q3[idx];
    float qx = a.x + bq.x + c.x + d.x, qy = a.y + bq.y + c.y + d.y;
    float qz = a.z + bq.z + c.z + d.z, qw = a.w + bq.w + c.w + d.w;
    sum += e.x * qx + e.y * qy + e.z * qz + e.w * qw;
  }
#pragma unroll
  for (int o = 32; o; o >>= 1) sum += __shfl_xor(sum, o);
  if (lane == 0) sc[(size_t)b * Sv + s] = sum;
}

// ---------------------------------------------------------------------------
// Per block (b, h-quarter): softmax over sc[b,:] (recomputed redundantly,
// cheap) then ctx[b, hc:hc+256] = sum_s attn[s] * enc[s,b,hc:hc+256].
__global__ void context_k(const float* __restrict__ sc_in,
                          const float* __restrict__ enc,
                          float* __restrict__ ctx) {
  int blk = blockIdx.x;                 // B * 4 = 512
  int b = blk >> 2, hc = (blk & 3) * 256;
  int t = threadIdx.x, lane = t & 63;
  __shared__ float a[256];
  __shared__ float redm[4], reds[4];
  float v = sc_in[(size_t)b * Sv + t];
  float m = v;
#pragma unroll
  for (int o = 32; o; o >>= 1) m = fmaxf(m, __shfl_xor(m, o));
  if (lane == 0) redm[t >> 6] = m;
  __syncthreads();
  m = fmaxf(fmaxf(redm[0], redm[1]), fmaxf(redm[2], redm[3]));
  float e = expf(v - m);
  float ssum = e;
#pragma unroll
  for (int o = 32; o; o >>= 1) ssum += __shfl_xor(ssum, o);
  if (lane == 0) reds[t >> 6] = ssum;
  __syncthreads();
  ssum = (reds[0] + reds[1]) + (reds[2] + reds[3]);
  a[t] = e / ssum;
  __syncthreads();

  float acc = 0.f;
  const float* ebase = enc + (size_t)b * Hv + hc + t;
#pragma unroll 4
  for (int s = 0; s < Sv; s++)
    acc += a[s] * ebase[(size_t)s * Bv * Hv];
  ctx[(size_t)b * Hv + hc + t] = acc;
}

// ---------------------------------------------------------------------------
__global__ void finish_cat(const float* __restrict__ catp,
                           float* __restrict__ cat) {
  int idx = blockIdx.x * 256 + threadIdx.x;  // 131072
  constexpr int ST = Bv * Hv;
  float v = catp[idx] + catp[ST + idx] + catp[2 * ST + idx] + catp[3 * ST + idx];
  cat[idx] = tanhf(v);
}

// ---------------------------------------------------------------------------
extern "C" void kernel_launch(void* const* d_in, const int* in_sizes, int n_in,
                              void* d_out, int out_size, void* d_ws,
                              size_t ws_size, hipStream_t stream) {
  const int*   ids      = (const int*)d_in[0];
  const float* h0       = (const float*)d_in[1];
  const float* c0       = (const float*)d_in[2];
  const float* enc      = (const float*)d_in[3];
  const float* emb      = (const float*)d_in[4];
  const float* w_ih0    = (const float*)d_in[5];
  const float* w_hh0    = (const float*)d_in[6];
  const float* b_ih0    = (const float*)d_in[7];
  const float* b_hh0    = (const float*)d_in[8];
  const float* w_ih1    = (const float*)d_in[9];
  const float* w_hh1    = (const float*)d_in[10];
  const float* b_ih1    = (const float*)d_in[11];
  const float* b_hh1    = (const float*)d_in[12];
  const float* attn_w   = (const float*)d_in[13];
  const float* attn_b   = (const float*)d_in[14];  // unused: cancels in softmax
  const float* concat_w = (const float*)d_in[15];
  const float* concat_b = (const float*)d_in[16];
  const float* out_w    = (const float*)d_in[17];
  const float* out_b    = (const float*)d_in[18];
  (void)attn_b;

  float* logits = (float*)d_out;                  // [128, 32000]
  float* hout   = logits + (size_t)Bv * Vv;       // [2, 128, 1024]
  float* cout   = hout + 2 * Bv * Hv;             // [2, 128, 1024]

  float* ws   = (float*)d_ws;
  float* G0p  = ws;                       // 3 * 524288
  float* G1p  = G0p + 3 * 524288;         // 4 * 524288
  float* qp   = G1p + 4 * (size_t)524288; // 4 * 131072
  float* catp = qp + 4 * 131072;          // 4 * 131072
  float* cat  = catp + 4 * 131072;        // 131072
  float* ctx  = cat + 131072;             // 131072
  float* sc   = ctx + 131072;             // 32768

  const float* h_b = hout + Bv * Hv;  // layer-1 h (rnn_out)

  // 1. LSTM layer 0 gates: K = 512(emb,gathered) + 1024(h0), 3-way split-K
  gemm_mfma<64, 32, 3, 0, 1, 4><<<dim3(128, 2, 3), 256, 0, stream>>>(
      ids, emb, Ev, Ev, h0, Hv, Hv, w_ih0, Ev, w_hh0, Hv, b_ih0, b_hh0,
      G0p, 4 * Hv, 4 * Hv);
  // 2. LSTM layer 0 pointwise (sums 3 partials); h -> hout[0]
  lstm_pw<3><<<512, 256, 0, stream>>>(G0p, c0, hout, cout);
  // 3. LSTM layer 1 gates: K = 1024(h_layer0) + 1024(h0[1]), 4-way split-K
  gemm_mfma<64, 32, 4, 0, 0, 4><<<dim3(128, 2, 4), 256, 0, stream>>>(
      nullptr, hout, Hv, Hv, h0 + Bv * Hv, Hv, Hv, w_ih1, Hv, w_hh1, Hv,
      b_ih1, b_hh1, G1p, 4 * Hv, 4 * Hv);
  // 4. LSTM layer 1 pointwise (sums 4 partials)
  lstm_pw<4><<<512, 256, 0, stream>>>(G1p, c0 + Bv * Hv, hout + Bv * Hv,
                                      cout + Bv * Hv);
  // 5. q = rnn @ attn_w (transposed in staging), 4-way split-K
  gemm_mfma<64, 32, 4, 1, 0, 4><<<dim3(32, 2, 4), 256, 0, stream>>>(
      nullptr, h_b, Hv, Hv, nullptr, 0, 0, attn_w, Hv,
      nullptr, 0, nullptr, nullptr, qp, Hv, Hv);
  // 6. scores (sums q partials inline)
  scores_k<<<8192, 256, 0, stream>>>(enc, qp, sc);
  // 7. softmax (redundant per block) + context
  context_k<<<512, 256, 0, stream>>>(sc, enc, ctx);
  // 8. concat gates: K = 1024(rnn) + 1024(ctx), 4-way split-K
  gemm_mfma<64, 32, 4, 0, 0, 4><<<dim3(32, 2, 4), 256, 0, stream>>>(
      nullptr, h_b, Hv, Hv, ctx, Hv, Hv, concat_w, 2 * Hv,
      concat_w + Hv, 2 * Hv, concat_b, nullptr, catp, Hv, Hv);
  // 9. cat = tanh(sum of partials)
  finish_cat<<<512, 256, 0, stream>>>(catp, cat);
  // 10. logits
  gemm_mfma<128, 64, 1, 0, 0, 3><<<dim3(500, 1, 1), 256, 0, stream>>>(
      nullptr, cat, Hv, Hv, nullptr, 0, 0, out_w, Hv, nullptr, 0,
      out_b, nullptr, logits, Vv, Vv);
}

// Round 5
// 179.786 us; speedup vs baseline: 1.7416x; 1.0235x over previous
//
#include <hip/hip_runtime.h>
#include <hip/hip_bf16.h>
#include <cstddef>
#include <cstdint>

// Problem dims
constexpr int Bv = 128;   // batch
constexpr int Sv = 256;   // src len
constexpr int Hv = 1024;  // hidden
constexpr int Ev = 512;   // embed
constexpr int Vv = 32000; // vocab

typedef __attribute__((ext_vector_type(4))) float f32x4;
typedef __attribute__((ext_vector_type(8))) short short8;

// f32x4 -> 4 packed bf16 (RNE). Written so the compiler emits
// v_cvt_pk_bf16_f32 pairs (hand-rolled bit math blocks the fusion).
__device__ __forceinline__ uint2 cvt4(float4 v) {
  union { __hip_bfloat162 b; unsigned u; } lo, hi;
  lo.b = __float22bfloat162_rn(float2{v.x, v.y});
  hi.b = __float22bfloat162_rn(float2{v.z, v.w});
  uint2 r;
  r.x = lo.u;
  r.y = hi.u;
  return r;
}
__device__ __forceinline__ unsigned short cvt1(float x) {
  union { __hip_bfloat16 b; unsigned short u; } c;
  c.b = __float2bfloat16(x);
  return c.u;
}

// ---------------------------------------------------------------------------
// MFMA GEMM with split-K partials:
//   Cp[z][m,n] = sum_{k in split z} A[m,k]*W[n,k]  (+bias on z==0)
// A = A1 (k<K1, optionally gathered emb rows) then A2. W row-major [N,K]
// unless WTR (W1 is [K,N], transposed during LDS staging).
// Partial z written at C + z*gridDim.y*BM*ldc. Consumers sum partials.
// ---------------------------------------------------------------------------
template <int BM, int BN, int SPLIT, int WTR, int GATHER, int MINW>
__global__ __launch_bounds__(256, MINW) void gemm_mfma(
    const int* __restrict__ ids,
    const float* __restrict__ A1, int lda1, int K1,
    const float* __restrict__ A2, int lda2, int K2,
    const float* __restrict__ W1, int ldw1,
    const float* __restrict__ W2, int ldw2,
    const float* __restrict__ bias1, const float* __restrict__ bias2,
    float* __restrict__ C, int ldc, int N) {
  constexpr int BK = 32, LP = 40;  // LDS row pitch (bf16), +8 pad
  constexpr int WAVES_N = (BN >= 64) ? 2 : 1;
  constexpr int WAVES_M = 4 / WAVES_N;
  constexpr int WM = BM / WAVES_M;
  constexpr int FM = WM / 16;
  constexpr int FN = 2;  // WN = 32
  constexpr int ACH = (BM * BK) / (4 * 256);
  constexpr int WCH = (BN * BK) / (4 * 256);

  __shared__ unsigned short Al[BM * LP];
  __shared__ unsigned short Wl[BN * LP];

  const int tid = threadIdx.x;
  const int wid = tid >> 6, lane = tid & 63;
  const int nBlock = blockIdx.x * BN;
  const int mBlock = blockIdx.y * BM;
  const int z = blockIdx.z;
  int wm, wn;
  if (WAVES_N == 2) { wm = (wid >> 1) * WM; wn = (wid & 1) * 32; }
  else              { wm = wid * WM;        wn = 0; }

  float4 av[ACH], wv[WCH];

  auto load_tile = [&](int kg) {
    const bool seg1 = kg < K1;
    const float* Wseg = seg1 ? W1 : W2;
    const int ldw = seg1 ? ldw1 : ldw2;
    const int kloc = seg1 ? kg : kg - K1;
#pragma unroll
    for (int i = 0; i < ACH; i++) {
      int c = tid + i * 256;
      int m = c >> 3, kq = (c & 7) << 2;
      const float* arow;
      if (seg1) {
        if (GATHER) arow = A1 + (size_t)ids[mBlock + m] * lda1;
        else        arow = A1 + (size_t)(mBlock + m) * lda1;
      } else {
        arow = A2 + (size_t)(mBlock + m) * lda2;
      }
      av[i] = *(const float4*)(arow + kloc + kq);
    }
    if (WTR) {
      int row = tid >> 3, colq = tid & 7;  // 32 k-rows x 8 n-quads
      wv[0] = *(const float4*)(Wseg + (size_t)(kloc + row) * ldw + nBlock + colq * 4);
    } else {
#pragma unroll
      for (int i = 0; i < WCH; i++) {
        int c = tid + i * 256;
        int n = c >> 3, kq = (c & 7) << 2;
        wv[i] = *(const float4*)(Wseg + (size_t)(nBlock + n) * ldw + kloc + kq);
      }
    }
  };

  const int KT = K1 + K2;
  const int KS = KT / SPLIT;          // per-split K (multiple of BK; segment-aligned)
  const int kbeg = z * KS;
  const int NS = KS / BK;
  load_tile(kbeg);
  f32x4 acc[FM][FN] = {};

  for (int step = 0; step < NS; ++step) {
    __syncthreads();  // previous iteration's fragment reads done
    // commit regs -> LDS (f32 -> bf16, packed 8B stores)
#pragma unroll
    for (int i = 0; i < ACH; i++) {
      int c = tid + i * 256;
      int m = c >> 3, kq = (c & 7) << 2;
      *(uint2*)&Al[m * LP + kq] = cvt4(av[i]);
    }
    if (WTR) {
      int row = tid >> 3, colq = tid & 7;
      Wl[(colq * 4 + 0) * LP + row] = cvt1(wv[0].x);
      Wl[(colq * 4 + 1) * LP + row] = cvt1(wv[0].y);
      Wl[(colq * 4 + 2) * LP + row] = cvt1(wv[0].z);
      Wl[(colq * 4 + 3) * LP + row] = cvt1(wv[0].w);
    } else {
#pragma unroll
      for (int i = 0; i < WCH; i++) {
        int c = tid + i * 256;
        int n = c >> 3, kq = (c & 7) << 2;
        *(uint2*)&Wl[n * LP + kq] = cvt4(wv[i]);
      }
    }
    __syncthreads();

    if (step + 1 < NS) load_tile(kbeg + (step + 1) * BK);  // prefetch

    const int klane = (lane >> 4) << 3;
    const int r = lane & 15;
    short8 af[FM], wf[FN];
#pragma unroll
    for (int f = 0; f < FM; f++)
      af[f] = *(const short8*)&Al[(wm + f * 16 + r) * LP + klane];
#pragma unroll
    for (int f = 0; f < FN; f++)
      wf[f] = *(const short8*)&Wl[(wn + f * 16 + r) * LP + klane];
#pragma unroll
    for (int fm = 0; fm < FM; fm++)
#pragma unroll
      for (int fn = 0; fn < FN; fn++)
        acc[fm][fn] = __builtin_amdgcn_mfma_f32_16x16x32_bf16(
            af[fm], wf[fn], acc[fm][fn], 0, 0, 0);
  }

  // Epilogue. D layout: col = lane&15, row = (lane>>4)*4 + j
  float* Cp = C + (size_t)z * gridDim.y * BM * ldc;
  const int col = lane & 15, rb = (lane >> 4) << 2;
#pragma unroll
  for (int fn = 0; fn < FN; fn++) {
    int n = nBlock + wn + fn * 16 + col;
    float bsum = 0.f;
    if (z == 0) {
      if (bias1) bsum += bias1[n];
      if (bias2) bsum += bias2[n];
    }
#pragma unroll
    for (int fm = 0; fm < FM; fm++) {
#pragma unroll
      for (int j = 0; j < 4; j++) {
        int m = mBlock + wm + fm * 16 + rb + j;
        Cp[(size_t)m * ldc + n] = acc[fm][fn][j] + bsum;
      }
    }
  }
}

// ---------------------------------------------------------------------------
template <int P>
__global__ void lstm_pw(const float* __restrict__ Gp,
                        const float* __restrict__ c_prev,
                        float* __restrict__ h_out,
                        float* __restrict__ c_out) {
  int i4 = blockIdx.x * 256 + threadIdx.x;  // 32768 float4 slots (B*H/4)
  int b = i4 >> 8, j4 = i4 & 255;
  float4 gi{}, gf{}, gg{}, go{};
#pragma unroll
  for (int p = 0; p < P; p++) {
    const float4* g = (const float4*)(Gp + (size_t)p * Bv * 4 * Hv + (size_t)b * 4096);
    float4 a = g[j4], bb = g[256 + j4], c = g[512 + j4], d = g[768 + j4];
    gi.x += a.x; gi.y += a.y; gi.z += a.z; gi.w += a.w;
    gf.x += bb.x; gf.y += bb.y; gf.z += bb.z; gf.w += bb.w;
    gg.x += c.x; gg.y += c.y; gg.z += c.z; gg.w += c.w;
    go.x += d.x; go.y += d.y; go.z += d.z; go.w += d.w;
  }
  float4 c4 = ((const float4*)c_prev)[i4];
  float4 h4, cn4;
  float* gip = &gi.x; float* gfp = &gf.x; float* ggp = &gg.x; float* gop = &go.x;
  float* cp = &c4.x; float* hp = &h4.x; float* cnp = &cn4.x;
#pragma unroll
  for (int u = 0; u < 4; u++) {
    float si = 1.f / (1.f + expf(-gip[u]));
    float sf = 1.f / (1.f + expf(-gfp[u]));
    float so = 1.f / (1.f + expf(-gop[u]));
    float cn = sf * cp[u] + si * tanhf(ggp[u]);
    hp[u] = so * tanhf(cn);
    cnp[u] = cn;
  }
  ((float4*)h_out)[i4] = h4;
  ((float4*)c_out)[i4] = cn4;
}

// ---------------------------------------------------------------------------
// scores[b,s] = <enc[s,b,:], q[b,:]>, q = sum of 4 split-K partials staged in
// LDS once per block (4 waves share b). attn_b term cancels in softmax.
__global__ void scores_k(const float* __restrict__ enc,
                         const float* __restrict__ qp,
                         float* __restrict__ sc) {
  int blk = blockIdx.x;           // B * S/4 = 8192
  int b = blk >> 6, s4 = blk & 63;
  int t = threadIdx.x;
  __shared__ float qs[1024];
  {
    const float4* q0 = (const float4*)(qp + (size_t)b * Hv);
    const float4* q1 = (const float4*)(qp + 1 * Bv * Hv + (size_t)b * Hv);
    const float4* q2 = (const float4*)(qp + 2 * Bv * Hv + (size_t)b * Hv);
    const float4* q3 = (const float4*)(qp + 3 * Bv * Hv + (size_t)b * Hv);
    float4 a = q0[t], bq = q1[t], c = q2[t], d = q3[t];
    float4 s;
    s.x = a.x + bq.x + c.x + d.x; s.y = a.y + bq.y + c.y + d.y;
    s.z = a.z + bq.z + c.z + d.z; s.w = a.w + bq.w + c.w + d.w;
    ((float4*)qs)[t] = s;
  }
  __syncthreads();
  int wid = t >> 6, lane = t & 63;
  int s = s4 * 4 + wid;
  const float4* e4 = (const float4*)(enc + ((size_t)s * Bv + b) * Hv);
  const float4* q4 = (const float4*)qs;
  float sum = 0.f;
#pragma unroll
  for (int i = 0; i < 4; i++) {
    int idx = lane + i * 64;
    float4 e = e4[idx], qq = q4[idx];
    sum += e.x * qq.x + e.y * qq.y + e.z * qq.z + e.w * qq.w;
  }
#pragma unroll
  for (int o = 32; o; o >>= 1) sum += __shfl_xor(sum, o);
  if (lane == 0) sc[(size_t)b * Sv + s] = sum;
}

// ---------------------------------------------------------------------------
// Per block (b, h-quarter): softmax over sc[b,:] (recomputed redundantly,
// cheap) then ctx[b, hc:hc+256] = sum_s attn[s] * enc[s,b,hc:hc+256].
__global__ void context_k(const float* __restrict__ sc_in,
                          const float* __restrict__ enc,
                          float* __restrict__ ctx) {
  int blk = blockIdx.x;                 // B * 4 = 512
  int b = blk >> 2, hc = (blk & 3) * 256;
  int t = threadIdx.x, lane = t & 63;
  __shared__ float a[256];
  __shared__ float redm[4], reds[4];
  float v = sc_in[(size_t)b * Sv + t];
  float m = v;
#pragma unroll
  for (int o = 32; o; o >>= 1) m = fmaxf(m, __shfl_xor(m, o));
  if (lane == 0) redm[t >> 6] = m;
  __syncthreads();
  m = fmaxf(fmaxf(redm[0], redm[1]), fmaxf(redm[2], redm[3]));
  float e = expf(v - m);
  float ssum = e;
#pragma unroll
  for (int o = 32; o; o >>= 1) ssum += __shfl_xor(ssum, o);
  if (lane == 0) reds[t >> 6] = ssum;
  __syncthreads();
  ssum = (reds[0] + reds[1]) + (reds[2] + reds[3]);
  a[t] = e / ssum;
  __syncthreads();

  float acc = 0.f;
  const float* ebase = enc + (size_t)b * Hv + hc + t;
#pragma unroll 8
  for (int s = 0; s < Sv; s++)
    acc += a[s] * ebase[(size_t)s * Bv * Hv];
  ctx[(size_t)b * Hv + hc + t] = acc;
}

// ---------------------------------------------------------------------------
__global__ void finish_cat(const float* __restrict__ catp,
                           float* __restrict__ cat) {
  int i4 = blockIdx.x * 256 + threadIdx.x;  // 32768 float4 slots
  constexpr int ST = Bv * Hv / 4;
  const float4* p = (const float4*)catp;
  float4 a = p[i4], b = p[ST + i4], c = p[2 * ST + i4], d = p[3 * ST + i4];
  float4 r;
  r.x = tanhf(a.x + b.x + c.x + d.x);
  r.y = tanhf(a.y + b.y + c.y + d.y);
  r.z = tanhf(a.z + b.z + c.z + d.z);
  r.w = tanhf(a.w + b.w + c.w + d.w);
  ((float4*)cat)[i4] = r;
}

// ---------------------------------------------------------------------------
extern "C" void kernel_launch(void* const* d_in, const int* in_sizes, int n_in,
                              void* d_out, int out_size, void* d_ws,
                              size_t ws_size, hipStream_t stream) {
  const int*   ids      = (const int*)d_in[0];
  const float* h0       = (const float*)d_in[1];
  const float* c0       = (const float*)d_in[2];
  const float* enc      = (const float*)d_in[3];
  const float* emb      = (const float*)d_in[4];
  const float* w_ih0    = (const float*)d_in[5];
  const float* w_hh0    = (const float*)d_in[6];
  const float* b_ih0    = (const float*)d_in[7];
  const float* b_hh0    = (const float*)d_in[8];
  const float* w_ih1    = (const float*)d_in[9];
  const float* w_hh1    = (const float*)d_in[10];
  const float* b_ih1    = (const float*)d_in[11];
  const float* b_hh1    = (const float*)d_in[12];
  const float* attn_w   = (const float*)d_in[13];
  const float* attn_b   = (const float*)d_in[14];  // cancels in softmax
  const float* concat_w = (const float*)d_in[15];
  const float* concat_b = (const float*)d_in[16];
  const float* out_w    = (const float*)d_in[17];
  const float* out_b    = (const float*)d_in[18];
  (void)attn_b;

  float* logits = (float*)d_out;                  // [128, 32000]
  float* hout   = logits + (size_t)Bv * Vv;       // [2, 128, 1024]
  float* cout   = hout + 2 * Bv * Hv;             // [2, 128, 1024]

  float* ws   = (float*)d_ws;
  float* G0p  = ws;                       // 3 * 524288
  float* G1p  = G0p + 3 * 524288;         // 4 * 524288
  float* qp   = G1p + 4 * (size_t)524288; // 4 * 131072
  float* catp = qp + 4 * 131072;          // 4 * 131072
  float* cat  = catp + 4 * 131072;        // 131072
  float* ctx  = cat + 131072;             // 131072
  float* sc   = ctx + 131072;             // 32768

  const float* h_b = hout + Bv * Hv;  // layer-1 h (rnn_out)

  // 1. LSTM layer 0 gates: K = 512(emb,gathered) + 1024(h0), 3-way split-K
  gemm_mfma<64, 32, 3, 0, 1, 4><<<dim3(128, 2, 3), 256, 0, stream>>>(
      ids, emb, Ev, Ev, h0, Hv, Hv, w_ih0, Ev, w_hh0, Hv, b_ih0, b_hh0,
      G0p, 4 * Hv, 4 * Hv);
  // 2. LSTM layer 0 pointwise (sums 3 partials); h -> hout[0]
  lstm_pw<3><<<128, 256, 0, stream>>>(G0p, c0, hout, cout);
  // 3. LSTM layer 1 gates: K = 1024(h_layer0) + 1024(h0[1]), 4-way split-K
  gemm_mfma<64, 32, 4, 0, 0, 4><<<dim3(128, 2, 4), 256, 0, stream>>>(
      nullptr, hout, Hv, Hv, h0 + Bv * Hv, Hv, Hv, w_ih1, Hv, w_hh1, Hv,
      b_ih1, b_hh1, G1p, 4 * Hv, 4 * Hv);
  // 4. LSTM layer 1 pointwise (sums 4 partials)
  lstm_pw<4><<<128, 256, 0, stream>>>(G1p, c0 + Bv * Hv, hout + Bv * Hv,
                                      cout + Bv * Hv);
  // 5. q = rnn @ attn_w (transposed in staging), 4-way split-K
  gemm_mfma<64, 32, 4, 1, 0, 4><<<dim3(32, 2, 4), 256, 0, stream>>>(
      nullptr, h_b, Hv, Hv, nullptr, 0, 0, attn_w, Hv,
      nullptr, 0, nullptr, nullptr, qp, Hv, Hv);
  // 6. scores (sums q partials via LDS once per block)
  scores_k<<<8192, 256, 0, stream>>>(enc, qp, sc);
  // 7. softmax (redundant per block) + context
  context_k<<<512, 256, 0, stream>>>(sc, enc, ctx);
  // 8. concat gates: K = 1024(rnn) + 1024(ctx), 4-way split-K
  gemm_mfma<64, 32, 4, 0, 0, 4><<<dim3(32, 2, 4), 256, 0, stream>>>(
      nullptr, h_b, Hv, Hv, ctx, Hv, Hv, concat_w, 2 * Hv,
      concat_w + Hv, 2 * Hv, concat_b, nullptr, catp, Hv, Hv);
  // 9. cat = tanh(sum of partials)
  finish_cat<<<128, 256, 0, stream>>>(catp, cat);
  // 10. logits: BM=64/BN=64 -> 1000 blocks (~4/CU) for latency hiding
  gemm_mfma<64, 64, 1, 0, 0, 4><<<dim3(500, 2, 1), 256, 0, stream>>>(
      nullptr, cat, Hv, Hv, nullptr, 0, 0, out_w, Hv, nullptr, 0,
      out_b, nullptr, logits, Vv, Vv);
}